// Round 5
// baseline (329.623 us; speedup 1.0000x reference)
//
#include <hip/hip_runtime.h>

typedef __bf16 bf16;
typedef __bf16 bf16x8 __attribute__((ext_vector_type(8)));
typedef __bf16 bf16x4 __attribute__((ext_vector_type(4)));
typedef float  floatx4 __attribute__((ext_vector_type(4)));

#define B_ 4
#define T_ 2048
#define E_ 1024
#define H_ 16
#define D_ 64
#define NTE_ (B_ * T_ * E_)  // 8388608 elems

#define NEG_BIG (-1e30f)
// q pre-scaled by 0.125*log2(e) => scores are S*log2e; exp(S-8.5) == exp2(S2 - SMAX2)
#define SMAX2 12.2629081f  // 8.5 * log2(e)

// ---- static device memory ------------------------------------------------
#define OFF_CQ 0ull
#define OFF_CK ((unsigned long long)NTE_)
#define OFF_CV (2ull * NTE_)
#define OFF_WQ (3ull * NTE_)
#define OFF_WK (OFF_WQ + 1048576ull)
#define OFF_WV (OFF_WK + 1048576ull)
#define OFF_WO (OFF_WV + 1048576ull)
__device__ bf16 g_conv[3ull * NTE_ + 4ull * 1048576ull];
// Pipeline scratch: qp | kp | (unused) | vt | op
__device__ bf16 g_scratch[5ull * NTE_];

__device__ __forceinline__ floatx4 mfma16(bf16x8 a, bf16x8 b, floatx4 c) {
  return __builtin_amdgcn_mfma_f32_16x16x32_bf16(a, b, c, 0, 0, 0);
}

__device__ __forceinline__ void async_copy16(void* lds, const void* g) {
  __builtin_amdgcn_global_load_lds(
      (const __attribute__((address_space(1))) unsigned int*)g,
      (__attribute__((address_space(3))) unsigned int*)lds, 16, 0, 0);
}

// ---------------------------------------------------------------------------
// One fused fp32->bf16 convert for the 7 MFMA-feeding tensors.
// ---------------------------------------------------------------------------
__global__ __launch_bounds__(256) void convert_all(const float4* __restrict__ q,
                                                   const float4* __restrict__ k,
                                                   const float4* __restrict__ v,
                                                   const float4* __restrict__ wq,
                                                   const float4* __restrict__ wk,
                                                   const float4* __restrict__ wv,
                                                   const float4* __restrict__ wo) {
  const float4* srcs[7] = {q, k, v, wq, wk, wv, wo};
  bf16x4* dsts[7] = {(bf16x4*)(g_conv + OFF_CQ), (bf16x4*)(g_conv + OFF_CK),
                     (bf16x4*)(g_conv + OFF_CV), (bf16x4*)(g_conv + OFF_WQ),
                     (bf16x4*)(g_conv + OFF_WK), (bf16x4*)(g_conv + OFF_WV),
                     (bf16x4*)(g_conv + OFF_WO)};
  const int n4s[7] = {NTE_ / 4, NTE_ / 4, NTE_ / 4, 262144, 262144, 262144, 262144};
  int i0 = blockIdx.x * 256 + threadIdx.x;
  int stride = gridDim.x * 256;
#pragma unroll
  for (int s = 0; s < 7; ++s) {
    const float4* sp = srcs[s];
    bf16x4* dp = dsts[s];
    int n4 = n4s[s];
    for (int i = i0; i < n4; i += stride) {
      float4 vv = sp[i];
      bf16x4 o;
      o[0] = (bf16)vv.x; o[1] = (bf16)vv.y; o[2] = (bf16)vv.z; o[3] = (bf16)vv.w;
      dp[i] = o;
    }
  }
}

// ---------------------------------------------------------------------------
// 128x256-tile pipelined GEMM core, BK=64 K-tiles, TWO barriers per K-tile.
//   C[M0..+128, N0..+256] = X[M0..,K=1024] . W[N0..,K=1024]^T  (+ epilogue)
// 512 threads = 8 waves (2M x 4N), per-wave 64x64 output, acc[4][4] (64 AGPR).
// LDS 96 KiB (allocated ONCE in the __global__ kernel and passed in).
// Grid is an exact multiple of 256 -> zero-tail packing.
//
// v5 change: removed the two PRE-MFMA barriers (round-4 had 4 barriers +
// 2 drains per 32 MFMA -> MfmaUtil pinned ~26%). Safety analysis:
//  * stage B(t+1)->B[p^1]: B[p^1] reads happened in P1 of t-1, lgkm-drained
//    before t-1's post-MFMA barrier; stage is issued after that barrier. OK.
//  * stage A(t+2)->A[p]: A[p] reads happened in P0 of t, lgkm-drained before
//    P0's MFMA, which precedes P0's post-MFMA barrier; stage issued in P1. OK.
//  * reads of tile t+1 are covered by counted vmcnt(2) at end of t
//    (queue then = [B(t+1), A(t+1) landed; A(t+2) left in flight]). OK.
// Waves now free-run between post-MFMA barriers: one wave's ds_reads overlap
// another's MFMAs (m97-style), with setprio arbitrating for the MFMA wave.
//
// Swizzle (conflict-free, measured): LDS slot s of row holds source chunk
// s^(row&7); staged via pre-swizzled global source (linear LDS dest as
// global_load_lds requires), read at slot (ks*4+q)^(r&7).
// Epilogue (template):
//   0: q-proj  -> +bias, RMSNorm, RoPE, *0.125*log2e, bf16 row-major
//   1: k-proj  -> +bias, RMSNorm, RoPE,               bf16 row-major
//   2: v-proj  -> +bias, bf16 TRANSPOSED write vt[(bh*64+d)*2048 + t]
//   3: out     -> +bias, fp32 row-major
// ---------------------------------------------------------------------------
template <int EPI>
__device__ __forceinline__ void gemm_core(char* __restrict__ smem,
                                          const bf16* __restrict__ X,
                                          const bf16* __restrict__ W,
                                          const float* __restrict__ bias,
                                          void* __restrict__ Yv, int M0, int N0,
                                          const float* __restrict__ cosb,
                                          const float* __restrict__ sinb) {
  constexpr int NT = 16;  // K / 64

  const int tid = threadIdx.x;
  const int w = tid >> 6;
  const int l = tid & 63;
  const int q = l >> 4;
  const int r = l & 15;
  const int lrow = l >> 3;
  const int rs7 = r & 7;
  const int wm = (w >> 2) * 64;
  const int wn = (w & 3) * 64;
  const int colb = ((l & 7) ^ lrow) << 4;  // pre-swizzled source column bytes
  const int sl0 = ((0 + q) ^ rs7) << 4;    // read slot, ks=0
  const int sl1 = ((4 + q) ^ rs7) << 4;    // read slot, ks=1

  char* const Ab = smem;            // A: buf p at p*16384
  char* const Bb = smem + 32768;    // B: buf p at p*32768
  const int aoff = (wm + r) * 128;
  const int boff = (wn + r) * 128;

  const char* gA = (const char*)X + (size_t)(M0 + w * 16 + lrow) * 2048 + colb;
  const char* gB = (const char*)W + (size_t)(N0 + w * 32 + lrow) * 2048 + colb;

  floatx4 acc[4][4];
#pragma unroll
  for (int mi = 0; mi < 4; ++mi)
#pragma unroll
    for (int ni = 0; ni < 4; ++ni) acc[mi][ni] = (floatx4){0.f, 0.f, 0.f, 0.f};

#define STA(p, t)                                              \
  do {                                                         \
    char* d_ = Ab + (p) * 16384 + w * 2048;                    \
    const char* s_ = gA + (size_t)(t) * 128;                   \
    async_copy16(d_, s_);                                      \
    async_copy16(d_ + 1024, s_ + 16384);                       \
  } while (0)
#define STB(p, t)                                              \
  do {                                                         \
    char* d_ = Bb + (p) * 32768 + w * 4096;                    \
    const char* s_ = gB + (size_t)(t) * 128;                   \
    async_copy16(d_, s_);                                      \
    async_copy16(d_ + 1024, s_ + 16384);                       \
    async_copy16(d_ + 2048, s_ + 32768);                       \
    async_copy16(d_ + 3072, s_ + 49152);                       \
  } while (0)

  // prologue: stage tiles 0 and 1; wait tile 0 only (queue left: B1,A1).
  STB(0, 0); STA(0, 0);
  STB(1, 1); STA(1, 1);
  asm volatile("s_waitcnt vmcnt(6)" ::: "memory");
  __builtin_amdgcn_s_barrier();

  bf16x8 af[4][2], bf0[2][2], bf1[2][2];

#pragma unroll 2
  for (int t = 0; t < NT; ++t) {
    const int p = t & 1;
    const char* rA = Ab + p * 16384;
    const char* rB = Bb + p * 32768;

    // ---- P0: read A (8 b128) + B01 (4); stage B(t+1); MFMA ni 0-1
#pragma unroll
    for (int mi = 0; mi < 4; ++mi) {
      af[mi][0] = *(const bf16x8*)(rA + aoff + mi * 2048 + sl0);
      af[mi][1] = *(const bf16x8*)(rA + aoff + mi * 2048 + sl1);
    }
#pragma unroll
    for (int ni = 0; ni < 2; ++ni) {
      bf0[ni][0] = *(const bf16x8*)(rB + boff + ni * 2048 + sl0);
      bf0[ni][1] = *(const bf16x8*)(rB + boff + ni * 2048 + sl1);
    }
    if (t >= 1 && t + 1 < NT) { STB(p ^ 1, t + 1); }
    asm volatile("s_waitcnt lgkmcnt(0)" ::: "memory");
    __builtin_amdgcn_sched_barrier(0);
    __builtin_amdgcn_s_setprio(1);
#pragma unroll
    for (int mi = 0; mi < 4; ++mi)
#pragma unroll
      for (int ni = 0; ni < 2; ++ni) {
        acc[mi][ni] = mfma16(af[mi][0], bf0[ni][0], acc[mi][ni]);
        acc[mi][ni] = mfma16(af[mi][1], bf0[ni][1], acc[mi][ni]);
      }
    __builtin_amdgcn_s_setprio(0);
    __builtin_amdgcn_s_barrier();

    // ---- P1: read B23 (4); stage A(t+2); MFMA ni 2-3; counted vmcnt
#pragma unroll
    for (int ni = 0; ni < 2; ++ni) {
      bf1[ni][0] = *(const bf16x8*)(rB + boff + (ni + 2) * 2048 + sl0);
      bf1[ni][1] = *(const bf16x8*)(rB + boff + (ni + 2) * 2048 + sl1);
    }
    if (t + 2 < NT) { STA(p, t + 2); }
    asm volatile("s_waitcnt lgkmcnt(0)" ::: "memory");
    __builtin_amdgcn_sched_barrier(0);
    __builtin_amdgcn_s_setprio(1);
#pragma unroll
    for (int mi = 0; mi < 4; ++mi)
#pragma unroll
      for (int ni = 0; ni < 2; ++ni) {
        acc[mi][ni + 2] = mfma16(af[mi][0], bf1[ni][0], acc[mi][ni + 2]);
        acc[mi][ni + 2] = mfma16(af[mi][1], bf1[ni][1], acc[mi][ni + 2]);
      }
    __builtin_amdgcn_s_setprio(0);
    if (t + 2 < NT) {
      asm volatile("s_waitcnt vmcnt(2)" ::: "memory");
    } else if (t + 1 < NT) {
      asm volatile("s_waitcnt vmcnt(0)" ::: "memory");
    }
    __builtin_amdgcn_s_barrier();
  }
#undef STA
#undef STB

  // ---------------- epilogue ----------------
  float bcol[4];
#pragma unroll
  for (int ni = 0; ni < 4; ++ni) bcol[ni] = bias[N0 + wn + ni * 16 + r];

  if (EPI == 0 || EPI == 1) {
    // +bias, RMSNorm over d=64, RoPE, (q: *0.125*log2e), bf16 row-major.
    const float post = (EPI == 0) ? 0.18033688f : 1.0f;
    bf16* Y = (bf16*)Yv;
#pragma unroll
    for (int mi = 0; mi < 4; ++mi) {
      const int rowbase = M0 + wm + mi * 16 + q * 4;
#pragma unroll
      for (int rr = 0; rr < 4; ++rr) {
        const int row = rowbase + rr;
        const int ts = row & (T_ - 1);
        float v0 = acc[mi][0][rr] + bcol[0];
        float v1 = acc[mi][1][rr] + bcol[1];
        float v2 = acc[mi][2][rr] + bcol[2];
        float v3 = acc[mi][3][rr] + bcol[3];
        float ss = v0 * v0 + v1 * v1 + v2 * v2 + v3 * v3;
        ss += __shfl_xor(ss, 1, 64);
        ss += __shfl_xor(ss, 2, 64);
        ss += __shfl_xor(ss, 4, 64);
        ss += __shfl_xor(ss, 8, 64);
        const float rs = rsqrtf(ss * (1.0f / 64.0f) + 1e-6f);
        const float y0 = v0 * rs, y1 = v1 * rs, y2 = v2 * rs, y3 = v3 * rs;
        const float c0 = cosb[ts * 32 + r], s0 = sinb[ts * 32 + r];
        const float c1 = cosb[ts * 32 + 16 + r], s1 = sinb[ts * 32 + 16 + r];
        bf16 o0 = (bf16)((y0 * c0 - y2 * s0) * post);
        bf16 o1 = (bf16)((y1 * c1 - y3 * s1) * post);
        bf16 o2 = (bf16)((y2 * c0 + y0 * s0) * post);
        bf16 o3 = (bf16)((y3 * c1 + y1 * s1) * post);
        bf16* yp = Y + (size_t)row * 1024 + N0 + wn + r;
        yp[0] = o0; yp[16] = o1; yp[32] = o2; yp[48] = o3;
      }
    }
  } else if (EPI == 2) {
    // +bias, transposed write: vt[((b*16+head)*64 + d)*2048 + t], bf16x4 on t.
    bf16* Y = (bf16*)Yv;
#pragma unroll
    for (int mi = 0; mi < 4; ++mi) {
      const int rowbase = M0 + wm + mi * 16 + q * 4;
      const int bb = rowbase >> 11;
      const int t0 = rowbase & (T_ - 1);
#pragma unroll
      for (int ni = 0; ni < 4; ++ni) {
        const int col = N0 + wn + ni * 16 + r;
        const int head = col >> 6;
        const int d = col & 63;
        bf16x4 pk;
#pragma unroll
        for (int rr = 0; rr < 4; ++rr) pk[rr] = (bf16)(acc[mi][ni][rr] + bcol[ni]);
        *(bf16x4*)(Y + ((size_t)(bb * 16 + head) * 64 + d) * 2048 + t0) = pk;
      }
    }
  } else {
    // fp32 row-major + bias.
    float* Y = (float*)Yv;
#pragma unroll
    for (int mi = 0; mi < 4; ++mi) {
      const int rowbase = M0 + wm + mi * 16 + q * 4;
#pragma unroll
      for (int ni = 0; ni < 4; ++ni) {
        const int col = N0 + wn + ni * 16 + r;
#pragma unroll
        for (int rr = 0; rr < 4; ++rr)
          Y[(size_t)(rowbase + rr) * 1024 + col] = acc[mi][ni][rr] + bcol[ni];
      }
    }
  }
}

// ---------------------------------------------------------------------------
// Projections: 768 blocks = 3 z x 64 mt x 4 nt, XCD-chunked (768%8==0).
// Fused epilogues: z0/z1 norm+rope (+q prescale), z2 transposed V write.
// ---------------------------------------------------------------------------
__global__ __launch_bounds__(512, 1) void gemm_qkv(const float* __restrict__ bq,
                                                   const float* __restrict__ bk,
                                                   const float* __restrict__ bv,
                                                   const float* __restrict__ cosb,
                                                   const float* __restrict__ sinb) {
  __shared__ __align__(16) char smem[98304];
  int bid = blockIdx.x;
  int s = (bid & 7) * 96 + (bid >> 3);  // bijective XCD chunking
  int z = s >> 8;
  int rem = s & 255;
  int mt = rem >> 2, nt = rem & 3;
  const bf16* X = g_conv + OFF_CQ + (unsigned long long)z * NTE_;
  const bf16* W = g_conv + OFF_WQ + (unsigned long long)z * 1048576ull;
  if (z == 0) {
    gemm_core<0>(smem, X, W, bq, (void*)g_scratch, mt * 128, nt * 256, cosb, sinb);
  } else if (z == 1) {
    gemm_core<1>(smem, X, W, bk, (void*)(g_scratch + (unsigned long long)NTE_),
                 mt * 128, nt * 256, cosb, sinb);
  } else {
    gemm_core<2>(smem, X, W, bv, (void*)(g_scratch + 3ull * NTE_),
                 mt * 128, nt * 256, nullptr, nullptr);
  }
}

// ---------------------------------------------------------------------------
// Final projection (fp32 out): 256 blocks = 64 mt x 4 nt, one clean round.
// ---------------------------------------------------------------------------
__global__ __launch_bounds__(512, 1) void gemm_out(const bf16* __restrict__ X,
                                                   const bf16* __restrict__ W,
                                                   const float* __restrict__ bias,
                                                   float* __restrict__ Y) {
  __shared__ __align__(16) char smem[98304];
  int bid = blockIdx.x;
  int s = (bid & 7) * 32 + (bid >> 3);  // bijective
  int mt = s >> 2, nt = s & 3;
  gemm_core<3>(smem, X, W, bias, (void*)Y, mt * 128, nt * 256, nullptr, nullptr);
}

// ---------------------------------------------------------------------------
// Flash attention, causal, STATIC-MAX softmax (see SMAX2 note above).
//  * 128 q-rows per block, 4 waves x 32 q-rows.
//  * SWAPPED QK mfma (A=K, B=Q) -> packed b64 P-strip stores.
//  * Grid 1024 = 8 xcd x 8 bh x 16 qt, heavy tiles first; K/V L2-local.
//  * v5: s_setprio(1) around MFMA clusters (T5; blocks are independent and
//    barrier-skewed, so prioritizing the MFMA-entering wave pays here).
// ---------------------------------------------------------------------------
#define KSTR 72
#define PSTR 72
__global__ __launch_bounds__(256, 4) void flash_attn() {
  const bf16* qp = g_scratch;
  const bf16* kp = g_scratch + (unsigned long long)NTE_;
  const bf16* vt = g_scratch + 3ull * NTE_;
  bf16* op = g_scratch + 4ull * NTE_;

  __shared__ __align__(16) bf16 sK[64 * KSTR];
  __shared__ __align__(16) bf16 sV[64 * KSTR];      // [d][key]
  __shared__ __align__(16) bf16 sP[4 * 32 * PSTR];  // wave-private [32 q][64 key]

  const int bid = blockIdx.x;
  const int xcd = bid & 7;
  const int lb = bid >> 3;              // 0..127 within XCD
  const int bh = xcd * 8 + (lb & 7);    // same bh -> same XCD
  const int qt = 15 - (lb >> 3);        // heavy q-tiles dispatched first
  const int h = bh & 15, b = bh >> 4;
  const int tid = threadIdx.x, w = tid >> 6, l = tid & 63, g = l >> 4, r = l & 15;
  const int Q0 = qt * 128;
  const int qw = Q0 + w * 32;           // this wave's first q-row

  const bf16* kbase = kp + (size_t)(b * T_) * E_ + h * D_;
  const bf16* vbase = vt + (size_t)bh * D_ * T_;
  bf16* pw = sP + w * (32 * PSTR);

  bf16x8 ones;
#pragma unroll
  for (int i = 0; i < 8; ++i) ones[i] = (bf16)1.0f;

  bf16x8 qa[2][2];
#pragma unroll
  for (int qb = 0; qb < 2; ++qb)
#pragma unroll
    for (int hf = 0; hf < 2; ++hf)
      qa[qb][hf] = *(const bf16x8*)(qp + (size_t)(b * T_ + qw + qb * 16 + r) * E_ +
                                    h * D_ + hf * 32 + g * 8);

  floatx4 o_acc[2][4], l_acc[2];
#pragma unroll
  for (int qb = 0; qb < 2; ++qb) {
    l_acc[qb] = (floatx4){0.f, 0.f, 0.f, 0.f};
#pragma unroll
    for (int dt = 0; dt < 4; ++dt) o_acc[qb][dt] = (floatx4){0.f, 0.f, 0.f, 0.f};
  }

  int srow[2], scc[2];
#pragma unroll
  for (int i = 0; i < 2; ++i) {
    int idx = i * 256 + tid;
    srow[i] = idx >> 3;
    scc[i] = (idx & 7) * 8;
  }

  bf16x8 kreg[2], vreg[2];
#pragma unroll
  for (int i = 0; i < 2; ++i) {
    kreg[i] = *(const bf16x8*)(kbase + (size_t)srow[i] * E_ + scc[i]);
    vreg[i] = *(const bf16x8*)(vbase + (size_t)srow[i] * T_ + scc[i]);
  }

  const int lastKt = Q0 + 64;
  for (int kt0 = 0; kt0 <= lastKt; kt0 += 64) {
    __syncthreads();
#pragma unroll
    for (int i = 0; i < 2; ++i) {
      *(bf16x8*)(sK + srow[i] * KSTR + scc[i]) = kreg[i];
      *(bf16x8*)(sV + srow[i] * KSTR + scc[i]) = vreg[i];
    }
    if (kt0 < lastKt) {
      int kt1 = kt0 + 64;
#pragma unroll
      for (int i = 0; i < 2; ++i) {
        kreg[i] = *(const bf16x8*)(kbase + (size_t)(kt1 + srow[i]) * E_ + scc[i]);
        vreg[i] = *(const bf16x8*)(vbase + (size_t)srow[i] * T_ + kt1 + scc[i]);
      }
    }
    __syncthreads();

    if (kt0 <= qw + 31) {
      const bool needMask = (kt0 + 63 > qw);

#pragma unroll
      for (int sc = 0; sc < 4; ++sc) {
        bf16x8 kb0 = *(const bf16x8*)(sK + (sc * 16 + r) * KSTR + g * 8);
        bf16x8 kb1 = *(const bf16x8*)(sK + (sc * 16 + r) * KSTR + 32 + g * 8);
        floatx4 s0 = (floatx4){0.f, 0.f, 0.f, 0.f};
        floatx4 s1 = (floatx4){0.f, 0.f, 0.f, 0.f};
        __builtin_amdgcn_s_setprio(1);
        s0 = mfma16(kb0, qa[0][0], s0);
        s0 = mfma16(kb1, qa[0][1], s0);
        s1 = mfma16(kb0, qa[1][0], s1);
        s1 = mfma16(kb1, qa[1][1], s1);
        __builtin_amdgcn_s_setprio(0);

        if (needMask) {
          int kg = kt0 + sc * 16 + g * 4;  // +rr
          int qg0 = qw + r;
          int qg1 = qw + 16 + r;
#pragma unroll
          for (int rr = 0; rr < 4; ++rr) {
            if (kg + rr > qg0) s0[rr] = NEG_BIG;
            if (kg + rr > qg1) s1[rr] = NEG_BIG;
          }
        }

        bf16x4 p0, p1;
#pragma unroll
        for (int rr = 0; rr < 4; ++rr) {
          p0[rr] = (bf16)exp2f(s0[rr] - SMAX2);
          p1[rr] = (bf16)exp2f(s1[rr] - SMAX2);
        }
        *(bf16x4*)(pw + r * PSTR + sc * 16 + g * 4) = p0;
        *(bf16x4*)(pw + (16 + r) * PSTR + sc * 16 + g * 4) = p1;
      }

#pragma unroll
      for (int kk = 0; kk < 2; ++kk) {
        bf16x8 vb[4];
#pragma unroll
        for (int dt = 0; dt < 4; ++dt)
          vb[dt] = *(const bf16x8*)(sV + (dt * 16 + r) * KSTR + kk * 32 + g * 8);
#pragma unroll
        for (int qb = 0; qb < 2; ++qb) {
          bf16x8 pa = *(const bf16x8*)(pw + (qb * 16 + r) * PSTR + kk * 32 + g * 8);
          __builtin_amdgcn_s_setprio(1);
          l_acc[qb] = mfma16(pa, ones, l_acc[qb]);
#pragma unroll
          for (int dt = 0; dt < 4; ++dt)
            o_acc[qb][dt] = mfma16(pa, vb[dt], o_acc[qb][dt]);
          __builtin_amdgcn_s_setprio(0);
        }
      }
    }
  }

  float linv[2][4];
#pragma unroll
  for (int qb = 0; qb < 2; ++qb)
#pragma unroll
    for (int rr = 0; rr < 4; ++rr) linv[qb][rr] = 1.0f / l_acc[qb][rr];
#pragma unroll
  for (int qb = 0; qb < 2; ++qb)
#pragma unroll
    for (int dt = 0; dt < 4; ++dt)
#pragma unroll
      for (int rr = 0; rr < 4; ++rr) {
        int t = qw + qb * 16 + g * 4 + rr;
        op[(size_t)(b * T_ + t) * E_ + h * D_ + dt * 16 + r] =
            (bf16)(o_acc[qb][dt][rr] * linv[qb][rr]);
      }
}

// ---------------------------------------------------------------------------
extern "C" void kernel_launch(void* const* d_in, const int* in_sizes, int n_in,
                              void* d_out, int out_size, void* d_ws, size_t ws_size,
                              hipStream_t stream) {
  float* out = (float*)d_out;  // fp32 output, per reference

  void* cvp_ = nullptr;
  void* sp_ = nullptr;
  (void)hipGetSymbolAddress(&cvp_, HIP_SYMBOL(g_conv));
  (void)hipGetSymbolAddress(&sp_, HIP_SYMBOL(g_scratch));
  bf16* cv = (bf16*)cvp_;
  bf16* sc = (bf16*)sp_;

  const float* cosb = (const float*)d_in[4];
  const float* sinb = (const float*)d_in[5];
  const float* bq = (const float*)d_in[7];
  const float* bk = (const float*)d_in[9];
  const float* bv = (const float*)d_in[11];
  const float* bo = (const float*)d_in[13];

  convert_all<<<dim3(1024), dim3(256), 0, stream>>>(
      (const float4*)d_in[0], (const float4*)d_in[1], (const float4*)d_in[2],
      (const float4*)d_in[6], (const float4*)d_in[8], (const float4*)d_in[10],
      (const float4*)d_in[12]);

  bf16* op = sc + 4ull * NTE_;

  gemm_qkv<<<dim3(768), dim3(512), 0, stream>>>(bq, bk, bv, cosb, sinb);
  flash_attn<<<dim3(1024), dim3(256), 0, stream>>>();
  gemm_out<<<dim3(256), dim3(512), 0, stream>>>(op, cv + OFF_WO, bo, out);
}

// Round 6
// 324.057 us; speedup vs baseline: 1.0172x; 1.0172x over previous
//
#include <hip/hip_runtime.h>

typedef __bf16 bf16;
typedef __bf16 bf16x8 __attribute__((ext_vector_type(8)));
typedef __bf16 bf16x4 __attribute__((ext_vector_type(4)));
typedef float  floatx4 __attribute__((ext_vector_type(4)));

#define B_ 4
#define T_ 2048
#define E_ 1024
#define H_ 16
#define D_ 64
#define NTE_ (B_ * T_ * E_)  // 8388608 elems

#define NEG_BIG (-1e30f)
// q pre-scaled by 0.125*log2(e) => scores are S*log2e; exp(S-8.5) == exp2(S2 - SMAX2)
#define SMAX2 12.2629081f  // 8.5 * log2(e)

// ---- static device memory ------------------------------------------------
#define OFF_CQ 0ull
#define OFF_CK ((unsigned long long)NTE_)
#define OFF_CV (2ull * NTE_)
#define OFF_WQ (3ull * NTE_)
#define OFF_WK (OFF_WQ + 1048576ull)
#define OFF_WV (OFF_WK + 1048576ull)
#define OFF_WO (OFF_WV + 1048576ull)
__device__ bf16 g_conv[3ull * NTE_ + 4ull * 1048576ull];
// Pipeline scratch: qp | kp | (unused) | vt | op
__device__ bf16 g_scratch[5ull * NTE_];

__device__ __forceinline__ floatx4 mfma16(bf16x8 a, bf16x8 b, floatx4 c) {
  return __builtin_amdgcn_mfma_f32_16x16x32_bf16(a, b, c, 0, 0, 0);
}

__device__ __forceinline__ void async_copy16(void* lds, const void* g) {
  __builtin_amdgcn_global_load_lds(
      (const __attribute__((address_space(1))) unsigned int*)g,
      (__attribute__((address_space(3))) unsigned int*)lds, 16, 0, 0);
}

// ---------------------------------------------------------------------------
// One fused fp32->bf16 convert for the 7 MFMA-feeding tensors.
// ---------------------------------------------------------------------------
__global__ __launch_bounds__(256) void convert_all(const float4* __restrict__ q,
                                                   const float4* __restrict__ k,
                                                   const float4* __restrict__ v,
                                                   const float4* __restrict__ wq,
                                                   const float4* __restrict__ wk,
                                                   const float4* __restrict__ wv,
                                                   const float4* __restrict__ wo) {
  const float4* srcs[7] = {q, k, v, wq, wk, wv, wo};
  bf16x4* dsts[7] = {(bf16x4*)(g_conv + OFF_CQ), (bf16x4*)(g_conv + OFF_CK),
                     (bf16x4*)(g_conv + OFF_CV), (bf16x4*)(g_conv + OFF_WQ),
                     (bf16x4*)(g_conv + OFF_WK), (bf16x4*)(g_conv + OFF_WV),
                     (bf16x4*)(g_conv + OFF_WO)};
  const int n4s[7] = {NTE_ / 4, NTE_ / 4, NTE_ / 4, 262144, 262144, 262144, 262144};
  int i0 = blockIdx.x * 256 + threadIdx.x;
  int stride = gridDim.x * 256;
#pragma unroll
  for (int s = 0; s < 7; ++s) {
    const float4* sp = srcs[s];
    bf16x4* dp = dsts[s];
    int n4 = n4s[s];
    for (int i = i0; i < n4; i += stride) {
      float4 vv = sp[i];
      bf16x4 o;
      o[0] = (bf16)vv.x; o[1] = (bf16)vv.y; o[2] = (bf16)vv.z; o[3] = (bf16)vv.w;
      dp[i] = o;
    }
  }
}

// ---------------------------------------------------------------------------
// 128x256-tile TRIPLE-BUFFERED single-phase GEMM core, BK=64 K-tiles.
//   C[M0..+128, N0..+256] = X[M0..,K=1024] . W[N0..,K=1024]^T  (+ epilogue)
// 512 threads = 8 waves (2M x 4N), per-wave 64x64 output, acc[4][4] (64 AGPR).
//
// v6 schedule (round-5 post-mortem: manual lgkmcnt(0)+sched_barrier drains
// were the stall — 2 full ds_read drains per K-tile with only 2 waves/SIMD):
//   * 3 LDS buffers (A 3x16K @0, B 3x32K @49152 = 144 KiB), distance-2
//     prefetch: stage(t+2) issued at top of iter t into the buffer whose
//     reads were barrier-confirmed at end of iter t-1 (cross-wave safe).
//   * Per K-tile: [issue stage(t+2)] -> 16 plain ds_read_b128 -> 32 MFMA
//     (COMPILER-scheduled, fine-grained lgkmcnt — no manual fences) ->
//     counted vmcnt(6) (waits stage(t+1) only; stage(t+2) stays in flight)
//     -> ONE barrier.
//   * Queue ledger: prologue stages S0..S2 (18 loads), vmcnt(12) waits S0;
//     steady state outstanding = {S(t+1), S(t+2)} = 12 loads, vmcnt(6)
//     waits S(t+1); t=NT-2 drains vmcnt(0); t=NT-1 no wait.
// Swizzle (conflict-free, measured): LDS slot s of row holds source chunk
// s^(row&7); staged via pre-swizzled global source (linear LDS dest as
// global_load_lds requires), read at slot (ks*4+q)^(r&7).
// Epilogue (template):
//   0: q-proj  -> +bias, RMSNorm, RoPE, *0.125*log2e, bf16 row-major
//   1: k-proj  -> +bias, RMSNorm, RoPE,               bf16 row-major
//   2: v-proj  -> +bias, bf16 TRANSPOSED write vt[(bh*64+d)*2048 + t]
//   3: out     -> +bias, fp32 row-major
// ---------------------------------------------------------------------------
template <int EPI>
__device__ __forceinline__ void gemm_core(char* __restrict__ smem,
                                          const bf16* __restrict__ X,
                                          const bf16* __restrict__ W,
                                          const float* __restrict__ bias,
                                          void* __restrict__ Yv, int M0, int N0,
                                          const float* __restrict__ cosb,
                                          const float* __restrict__ sinb) {
  constexpr int NT = 16;  // K / 64

  const int tid = threadIdx.x;
  const int w = tid >> 6;
  const int l = tid & 63;
  const int q = l >> 4;
  const int r = l & 15;
  const int lrow = l >> 3;
  const int rs7 = r & 7;
  const int wm = (w >> 2) * 64;
  const int wn = (w & 3) * 64;
  const int colb = ((l & 7) ^ lrow) << 4;  // pre-swizzled source column bytes
  const int sl0 = ((0 + q) ^ rs7) << 4;    // read slot, ks=0
  const int sl1 = ((4 + q) ^ rs7) << 4;    // read slot, ks=1

  char* const Ab = smem;            // A: buf i at i*16384 (3 bufs)
  char* const Bb = smem + 49152;    // B: buf i at i*32768 (3 bufs)
  const int aoff = (wm + r) * 128;
  const int boff = (wn + r) * 128;

  const char* gA = (const char*)X + (size_t)(M0 + w * 16 + lrow) * 2048 + colb;
  const char* gB = (const char*)W + (size_t)(N0 + w * 32 + lrow) * 2048 + colb;

  floatx4 acc[4][4];
#pragma unroll
  for (int mi = 0; mi < 4; ++mi)
#pragma unroll
    for (int ni = 0; ni < 4; ++ni) acc[mi][ni] = (floatx4){0.f, 0.f, 0.f, 0.f};

#define STA(bi, t)                                             \
  do {                                                         \
    char* d_ = Ab + (bi) * 16384 + w * 2048;                   \
    const char* s_ = gA + (size_t)(t) * 128;                   \
    async_copy16(d_, s_);                                      \
    async_copy16(d_ + 1024, s_ + 16384);                       \
  } while (0)
#define STB(bi, t)                                             \
  do {                                                         \
    char* d_ = Bb + (bi) * 32768 + w * 4096;                   \
    const char* s_ = gB + (size_t)(t) * 128;                   \
    async_copy16(d_, s_);                                      \
    async_copy16(d_ + 1024, s_ + 16384);                       \
    async_copy16(d_ + 2048, s_ + 32768);                       \
    async_copy16(d_ + 3072, s_ + 49152);                       \
  } while (0)

  // prologue: stage tiles 0,1,2 into bufs 0,1,2; wait tile 0 (leave 12).
  STB(0, 0); STA(0, 0);
  STB(1, 1); STA(1, 1);
  STB(2, 2); STA(2, 2);
  asm volatile("s_waitcnt vmcnt(12)" ::: "memory");
  asm volatile("s_barrier" ::: "memory");

#pragma unroll
  for (int t = 0; t < NT; ++t) {
    const int ib = t % 3;        // compile-time after full unroll
    const int st = (t + 2) % 3;  // stage target = buffer read in iter t-1

    if (t >= 1 && t + 2 < NT) { STB(st, t + 2); STA(st, t + 2); }

    const char* rA = Ab + ib * 16384;
    const char* rB = Bb + ib * 32768;

    bf16x8 af[4][2], bv[4][2];
#pragma unroll
    for (int mi = 0; mi < 4; ++mi) {
      af[mi][0] = *(const bf16x8*)(rA + aoff + mi * 2048 + sl0);
      af[mi][1] = *(const bf16x8*)(rA + aoff + mi * 2048 + sl1);
    }
#pragma unroll
    for (int ni = 0; ni < 4; ++ni) {
      bv[ni][0] = *(const bf16x8*)(rB + boff + ni * 2048 + sl0);
      bv[ni][1] = *(const bf16x8*)(rB + boff + ni * 2048 + sl1);
    }
    // No manual lgkm fence: plain loads -> compiler emits fine-grained
    // lgkmcnt and interleaves MFMAs with the read stream.
#pragma unroll
    for (int mi = 0; mi < 4; ++mi)
#pragma unroll
      for (int ni = 0; ni < 4; ++ni) {
        acc[mi][ni] = mfma16(af[mi][0], bv[ni][0], acc[mi][ni]);
        acc[mi][ni] = mfma16(af[mi][1], bv[ni][1], acc[mi][ni]);
      }

    if (t + 3 <= NT) {
      asm volatile("s_waitcnt vmcnt(6)" ::: "memory");   // S(t+1) landed
    } else if (t + 2 == NT) {
      asm volatile("s_waitcnt vmcnt(0)" ::: "memory");   // final drain
    }
    if (t + 1 < NT) asm volatile("s_barrier" ::: "memory");
  }
#undef STA
#undef STB

  // ---------------- epilogue ----------------
  float bcol[4];
#pragma unroll
  for (int ni = 0; ni < 4; ++ni) bcol[ni] = bias[N0 + wn + ni * 16 + r];

  if (EPI == 0 || EPI == 1) {
    // +bias, RMSNorm over d=64, RoPE, (q: *0.125*log2e), bf16 row-major.
    const float post = (EPI == 0) ? 0.18033688f : 1.0f;
    bf16* Y = (bf16*)Yv;
#pragma unroll
    for (int mi = 0; mi < 4; ++mi) {
      const int rowbase = M0 + wm + mi * 16 + q * 4;
#pragma unroll
      for (int rr = 0; rr < 4; ++rr) {
        const int row = rowbase + rr;
        const int ts = row & (T_ - 1);
        float v0 = acc[mi][0][rr] + bcol[0];
        float v1 = acc[mi][1][rr] + bcol[1];
        float v2 = acc[mi][2][rr] + bcol[2];
        float v3 = acc[mi][3][rr] + bcol[3];
        float ss = v0 * v0 + v1 * v1 + v2 * v2 + v3 * v3;
        ss += __shfl_xor(ss, 1, 64);
        ss += __shfl_xor(ss, 2, 64);
        ss += __shfl_xor(ss, 4, 64);
        ss += __shfl_xor(ss, 8, 64);
        const float rs = rsqrtf(ss * (1.0f / 64.0f) + 1e-6f);
        const float y0 = v0 * rs, y1 = v1 * rs, y2 = v2 * rs, y3 = v3 * rs;
        const float c0 = cosb[ts * 32 + r], s0 = sinb[ts * 32 + r];
        const float c1 = cosb[ts * 32 + 16 + r], s1 = sinb[ts * 32 + 16 + r];
        bf16 o0 = (bf16)((y0 * c0 - y2 * s0) * post);
        bf16 o1 = (bf16)((y1 * c1 - y3 * s1) * post);
        bf16 o2 = (bf16)((y2 * c0 + y0 * s0) * post);
        bf16 o3 = (bf16)((y3 * c1 + y1 * s1) * post);
        bf16* yp = Y + (size_t)row * 1024 + N0 + wn + r;
        yp[0] = o0; yp[16] = o1; yp[32] = o2; yp[48] = o3;
      }
    }
  } else if (EPI == 2) {
    // +bias, transposed write: vt[((b*16+head)*64 + d)*2048 + t], bf16x4 on t.
    bf16* Y = (bf16*)Yv;
#pragma unroll
    for (int mi = 0; mi < 4; ++mi) {
      const int rowbase = M0 + wm + mi * 16 + q * 4;
      const int bb = rowbase >> 11;
      const int t0 = rowbase & (T_ - 1);
#pragma unroll
      for (int ni = 0; ni < 4; ++ni) {
        const int col = N0 + wn + ni * 16 + r;
        const int head = col >> 6;
        const int d = col & 63;
        bf16x4 pk;
#pragma unroll
        for (int rr = 0; rr < 4; ++rr) pk[rr] = (bf16)(acc[mi][ni][rr] + bcol[ni]);
        *(bf16x4*)(Y + ((size_t)(bb * 16 + head) * 64 + d) * 2048 + t0) = pk;
      }
    }
  } else {
    // fp32 row-major + bias.
    float* Y = (float*)Yv;
#pragma unroll
    for (int mi = 0; mi < 4; ++mi) {
      const int rowbase = M0 + wm + mi * 16 + q * 4;
#pragma unroll
      for (int ni = 0; ni < 4; ++ni) {
        const int col = N0 + wn + ni * 16 + r;
#pragma unroll
        for (int rr = 0; rr < 4; ++rr)
          Y[(size_t)(rowbase + rr) * 1024 + col] = acc[mi][ni][rr] + bcol[ni];
      }
    }
  }
}

// ---------------------------------------------------------------------------
// Projections: 768 blocks = 3 z x 64 mt x 4 nt, XCD-chunked (768%8==0).
// Fused epilogues: z0/z1 norm+rope (+q prescale), z2 transposed V write.
// ---------------------------------------------------------------------------
__global__ __launch_bounds__(512, 1) void gemm_qkv(const float* __restrict__ bq,
                                                   const float* __restrict__ bk,
                                                   const float* __restrict__ bv,
                                                   const float* __restrict__ cosb,
                                                   const float* __restrict__ sinb) {
  __shared__ __align__(16) char smem[147456];
  int bid = blockIdx.x;
  int s = (bid & 7) * 96 + (bid >> 3);  // bijective XCD chunking
  int z = s >> 8;
  int rem = s & 255;
  int mt = rem >> 2, nt = rem & 3;
  const bf16* X = g_conv + OFF_CQ + (unsigned long long)z * NTE_;
  const bf16* W = g_conv + OFF_WQ + (unsigned long long)z * 1048576ull;
  if (z == 0) {
    gemm_core<0>(smem, X, W, bq, (void*)g_scratch, mt * 128, nt * 256, cosb, sinb);
  } else if (z == 1) {
    gemm_core<1>(smem, X, W, bk, (void*)(g_scratch + (unsigned long long)NTE_),
                 mt * 128, nt * 256, cosb, sinb);
  } else {
    gemm_core<2>(smem, X, W, bv, (void*)(g_scratch + 3ull * NTE_),
                 mt * 128, nt * 256, nullptr, nullptr);
  }
}

// ---------------------------------------------------------------------------
// Final projection (fp32 out): 256 blocks = 64 mt x 4 nt, one clean round.
// ---------------------------------------------------------------------------
__global__ __launch_bounds__(512, 1) void gemm_out(const bf16* __restrict__ X,
                                                   const bf16* __restrict__ W,
                                                   const float* __restrict__ bias,
                                                   float* __restrict__ Y) {
  __shared__ __align__(16) char smem[147456];
  int bid = blockIdx.x;
  int s = (bid & 7) * 32 + (bid >> 3);  // bijective
  int mt = s >> 2, nt = s & 3;
  gemm_core<3>(smem, X, W, bias, (void*)Y, mt * 128, nt * 256, nullptr, nullptr);
}

// ---------------------------------------------------------------------------
// Flash attention, causal, STATIC-MAX softmax (see SMAX2 note above).
//  * 128 q-rows per block, 4 waves x 32 q-rows.
//  * SWAPPED QK mfma (A=K, B=Q) -> packed b64 P-strip stores.
//  * Grid 1024 = 8 xcd x 8 bh x 16 qt, heavy tiles first; K/V L2-local.
//  * v6: setprio REVERTED (round-5 A/B: -6 µs on this lockstep structure,
//    matching m190's GEMM null/negative — setprio only pays with role-split).
// ---------------------------------------------------------------------------
#define KSTR 72
#define PSTR 72
__global__ __launch_bounds__(256, 4) void flash_attn() {
  const bf16* qp = g_scratch;
  const bf16* kp = g_scratch + (unsigned long long)NTE_;
  const bf16* vt = g_scratch + 3ull * NTE_;
  bf16* op = g_scratch + 4ull * NTE_;

  __shared__ __align__(16) bf16 sK[64 * KSTR];
  __shared__ __align__(16) bf16 sV[64 * KSTR];      // [d][key]
  __shared__ __align__(16) bf16 sP[4 * 32 * PSTR];  // wave-private [32 q][64 key]

  const int bid = blockIdx.x;
  const int xcd = bid & 7;
  const int lb = bid >> 3;              // 0..127 within XCD
  const int bh = xcd * 8 + (lb & 7);    // same bh -> same XCD
  const int qt = 15 - (lb >> 3);        // heavy q-tiles dispatched first
  const int h = bh & 15, b = bh >> 4;
  const int tid = threadIdx.x, w = tid >> 6, l = tid & 63, g = l >> 4, r = l & 15;
  const int Q0 = qt * 128;
  const int qw = Q0 + w * 32;           // this wave's first q-row

  const bf16* kbase = kp + (size_t)(b * T_) * E_ + h * D_;
  const bf16* vbase = vt + (size_t)bh * D_ * T_;
  bf16* pw = sP + w * (32 * PSTR);

  bf16x8 ones;
#pragma unroll
  for (int i = 0; i < 8; ++i) ones[i] = (bf16)1.0f;

  bf16x8 qa[2][2];
#pragma unroll
  for (int qb = 0; qb < 2; ++qb)
#pragma unroll
    for (int hf = 0; hf < 2; ++hf)
      qa[qb][hf] = *(const bf16x8*)(qp + (size_t)(b * T_ + qw + qb * 16 + r) * E_ +
                                    h * D_ + hf * 32 + g * 8);

  floatx4 o_acc[2][4], l_acc[2];
#pragma unroll
  for (int qb = 0; qb < 2; ++qb) {
    l_acc[qb] = (floatx4){0.f, 0.f, 0.f, 0.f};
#pragma unroll
    for (int dt = 0; dt < 4; ++dt) o_acc[qb][dt] = (floatx4){0.f, 0.f, 0.f, 0.f};
  }

  int srow[2], scc[2];
#pragma unroll
  for (int i = 0; i < 2; ++i) {
    int idx = i * 256 + tid;
    srow[i] = idx >> 3;
    scc[i] = (idx & 7) * 8;
  }

  bf16x8 kreg[2], vreg[2];
#pragma unroll
  for (int i = 0; i < 2; ++i) {
    kreg[i] = *(const bf16x8*)(kbase + (size_t)srow[i] * E_ + scc[i]);
    vreg[i] = *(const bf16x8*)(vbase + (size_t)srow[i] * T_ + scc[i]);
  }

  const int lastKt = Q0 + 64;
  for (int kt0 = 0; kt0 <= lastKt; kt0 += 64) {
    __syncthreads();
#pragma unroll
    for (int i = 0; i < 2; ++i) {
      *(bf16x8*)(sK + srow[i] * KSTR + scc[i]) = kreg[i];
      *(bf16x8*)(sV + srow[i] * KSTR + scc[i]) = vreg[i];
    }
    if (kt0 < lastKt) {
      int kt1 = kt0 + 64;
#pragma unroll
      for (int i = 0; i < 2; ++i) {
        kreg[i] = *(const bf16x8*)(kbase + (size_t)(kt1 + srow[i]) * E_ + scc[i]);
        vreg[i] = *(const bf16x8*)(vbase + (size_t)srow[i] * T_ + kt1 + scc[i]);
      }
    }
    __syncthreads();

    if (kt0 <= qw + 31) {
      const bool needMask = (kt0 + 63 > qw);

#pragma unroll
      for (int sc = 0; sc < 4; ++sc) {
        bf16x8 kb0 = *(const bf16x8*)(sK + (sc * 16 + r) * KSTR + g * 8);
        bf16x8 kb1 = *(const bf16x8*)(sK + (sc * 16 + r) * KSTR + 32 + g * 8);
        floatx4 s0 = (floatx4){0.f, 0.f, 0.f, 0.f};
        floatx4 s1 = (floatx4){0.f, 0.f, 0.f, 0.f};
        s0 = mfma16(kb0, qa[0][0], s0);
        s0 = mfma16(kb1, qa[0][1], s0);
        s1 = mfma16(kb0, qa[1][0], s1);
        s1 = mfma16(kb1, qa[1][1], s1);

        if (needMask) {
          int kg = kt0 + sc * 16 + g * 4;  // +rr
          int qg0 = qw + r;
          int qg1 = qw + 16 + r;
#pragma unroll
          for (int rr = 0; rr < 4; ++rr) {
            if (kg + rr > qg0) s0[rr] = NEG_BIG;
            if (kg + rr > qg1) s1[rr] = NEG_BIG;
          }
        }

        bf16x4 p0, p1;
#pragma unroll
        for (int rr = 0; rr < 4; ++rr) {
          p0[rr] = (bf16)exp2f(s0[rr] - SMAX2);
          p1[rr] = (bf16)exp2f(s1[rr] - SMAX2);
        }
        *(bf16x4*)(pw + r * PSTR + sc * 16 + g * 4) = p0;
        *(bf16x4*)(pw + (16 + r) * PSTR + sc * 16 + g * 4) = p1;
      }

#pragma unroll
      for (int kk = 0; kk < 2; ++kk) {
        bf16x8 vb[4];
#pragma unroll
        for (int dt = 0; dt < 4; ++dt)
          vb[dt] = *(const bf16x8*)(sV + (dt * 16 + r) * KSTR + kk * 32 + g * 8);
#pragma unroll
        for (int qb = 0; qb < 2; ++qb) {
          bf16x8 pa = *(const bf16x8*)(pw + (qb * 16 + r) * PSTR + kk * 32 + g * 8);
          l_acc[qb] = mfma16(pa, ones, l_acc[qb]);
#pragma unroll
          for (int dt = 0; dt < 4; ++dt)
            o_acc[qb][dt] = mfma16(pa, vb[dt], o_acc[qb][dt]);
        }
      }
    }
  }

  float linv[2][4];
#pragma unroll
  for (int qb = 0; qb < 2; ++qb)
#pragma unroll
    for (int rr = 0; rr < 4; ++rr) linv[qb][rr] = 1.0f / l_acc[qb][rr];
#pragma unroll
  for (int qb = 0; qb < 2; ++qb)
#pragma unroll
    for (int dt = 0; dt < 4; ++dt)
#pragma unroll
      for (int rr = 0; rr < 4; ++rr) {
        int t = qw + qb * 16 + g * 4 + rr;
        op[(size_t)(b * T_ + t) * E_ + h * D_ + dt * 16 + r] =
            (bf16)(o_acc[qb][dt][rr] * linv[qb][rr]);
      }
}

// ---------------------------------------------------------------------------
extern "C" void kernel_launch(void* const* d_in, const int* in_sizes, int n_in,
                              void* d_out, int out_size, void* d_ws, size_t ws_size,
                              hipStream_t stream) {
  float* out = (float*)d_out;  // fp32 output, per reference

  void* cvp_ = nullptr;
  void* sp_ = nullptr;
  (void)hipGetSymbolAddress(&cvp_, HIP_SYMBOL(g_conv));
  (void)hipGetSymbolAddress(&sp_, HIP_SYMBOL(g_scratch));
  bf16* cv = (bf16*)cvp_;
  bf16* sc = (bf16*)sp_;

  const float* cosb = (const float*)d_in[4];
  const float* sinb = (const float*)d_in[5];
  const float* bq = (const float*)d_in[7];
  const float* bk = (const float*)d_in[9];
  const float* bv = (const float*)d_in[11];
  const float* bo = (const float*)d_in[13];

  convert_all<<<dim3(1024), dim3(256), 0, stream>>>(
      (const float4*)d_in[0], (const float4*)d_in[1], (const float4*)d_in[2],
      (const float4*)d_in[6], (const float4*)d_in[8], (const float4*)d_in[10],
      (const float4*)d_in[12]);

  bf16* op = sc + 4ull * NTE_;

  gemm_qkv<<<dim3(768), dim3(512), 0, stream>>>(bq, bk, bv, cosb, sinb);
  flash_attn<<<dim3(1024), dim3(256), 0, stream>>>();
  gemm_out<<<dim3(256), dim3(512), 0, stream>>>(op, cv + OFF_WO, bo, out);
}